// Round 8
// baseline (486.450 us; speedup 1.0000x reference)
//
#include <hip/hip_runtime.h>

// WindowAttention: B_=4096 windows, N=49, DIM=128, NH=4, HD=32, nW=64.
// 512 threads = 8 waves; wave w -> (head = w&3, m-half = w>>2).
// bf16 MFMA 16x16x32. S computed transposed (S^T = K*Q^T): softmax rows in-lane,
// P feeds PV as B-fragment via shuffles. Q never touches LDS (R7-verified
// swapped-MFMA + in-wave exchange).
// R8 = R7 + persistent blocks with cross-window prefetch pipeline:
//  - grid 768 (3 blocks/CU x 256 CU); each block loops ~5-6 windows.
//  - next window's x staged global->regs DURING phase 1/2, regs->LDS after
//    phase 2 (T14 issue-early/write-late across windows). Phase-0 HBM latency
//    (the dominant exposed stall: every pipe <25% busy) hides under compute.
//  - xs is its own LDS buffer (no union) -> 2 barriers/window (was 3).
//    LDS = kk 16384 + vt 18432 + xs 17408 = 52224 B -> 3 blocks/CU.
//  - s_setprio removed (R7: MfmaUtil 9.2->8.3, T5-null regime).
// R5 lesson: stay well under the ~85-reg unified cap at (512,6); staging adds
// only 16 VGPR. Tripwire for spill = WRITE_SIZE >> 100 MB.

typedef short bf16x8 __attribute__((ext_vector_type(8)));
typedef float f32x4 __attribute__((ext_vector_type(4)));

#define DEVI __device__ __forceinline__

DEVI unsigned short f2b(float f) {   // fp32 -> bf16 bits, round-to-nearest-even
    unsigned u = __builtin_bit_cast(unsigned, f);
    u += 0x7fffu + ((u >> 16) & 1u);
    return (unsigned short)(u >> 16);
}

DEVI unsigned pack2(float lo, float hi) {
    return (unsigned)f2b(lo) | ((unsigned)f2b(hi) << 16);
}

#define WS_BIAS_OFF 98304
#define WS_COMB_OFF 131072
#define COMB_ELEMS  802816u   // 256 * 49 * 64 (padded n-dim to 64)
#define WS_NEED     (131072u + COMB_ELEMS * 4u)
#define GRID_WS     768

__global__ __launch_bounds__(256) void prep_kernel(
    const float* __restrict__ qkvw, const float* __restrict__ qkvb,
    const float* __restrict__ maskg, const float* __restrict__ relt,
    unsigned short* __restrict__ wb, float* __restrict__ bb,
    float* __restrict__ comb)
{
    const int g = blockIdx.x * 256 + threadIdx.x;
    if (g < 49152) {
        const int row = g >> 7, col = g & 127;
        const int s = row >> 7, r7 = row & 127, hh = r7 >> 5, d = r7 & 31;
        const int c = hh * 96 + d * 3 + s;          // torch row
        const float mul = (s == 0) ? 0.17677669529663687f : 1.0f;
        wb[row * 128 + col] = f2b(qkvw[c * 128 + col] * mul);
    } else if (g < 49536) {
        const int row = g - 49152;
        const int s = row >> 7, r7 = row & 127, hh = r7 >> 5, d = r7 & 31;
        const int c = hh * 96 + d * 3 + s;
        const float mul = (s == 0) ? 0.17677669529663687f : 1.0f;
        bb[row] = qkvb[c] * mul;
    } else {
        const unsigned g2 = (unsigned)(g - 49536);
        if (g2 < COMB_ELEMS) {
            const int wh = g2 / 3136;
            const int rr = g2 - wh * 3136;
            const int m = rr >> 6, n = rr & 63;
            const int w = wh >> 2, hh = wh & 3;
            float v = -1e30f;
            if (n < 49) {
                const int md = m / 7, mm = m - md * 7;
                const int nd = n / 7, nm = n - nd * 7;
                const int ridx = (md - nd + 6) * 13 + (mm - nm + 6);
                v = maskg[w * 2401 + m * 49 + n] + relt[ridx * 4 + hh];
            }
            comb[g2] = v;
        }
    }
}

// ---------------- workspace (fast) kernel ----------------
// LDS: kk 16384 + vt 18432 + xs 17408 = 52224 B -> 3 blocks/CU.
struct __align__(16) SmemWS {
    unsigned short kk[4][64][32];      // K [head][n][d]
    unsigned short vt[4][32][72];      // V^T [head][d][n], 144 B rows
    unsigned short xs[64][136];        // staged x, 272 B rows
};

DEVI void stage_load(const float* __restrict__ xg, int w, int tid,
                     float4& r0, float4& r1, float4& r2, float4& r3) {
    const float4* xb = (const float4*)(xg + (size_t)w * 6272);
    r0 = xb[tid];
    r1 = xb[512 + tid];
    r2 = xb[1024 + tid];
    if (tid < 32) r3 = xb[1536 + tid];
}

DEVI void stage_write(unsigned short (*xs)[136], int tid,
                      const float4& r0, const float4& r1,
                      const float4& r2, const float4& r3) {
    const int i0 = tid, i1 = 512 + tid, i2 = 1024 + tid;
    *(ushort4*)&xs[i0 >> 5][(i0 & 31) << 2] =
        make_ushort4(f2b(r0.x), f2b(r0.y), f2b(r0.z), f2b(r0.w));
    *(ushort4*)&xs[i1 >> 5][(i1 & 31) << 2] =
        make_ushort4(f2b(r1.x), f2b(r1.y), f2b(r1.z), f2b(r1.w));
    *(ushort4*)&xs[i2 >> 5][(i2 & 31) << 2] =
        make_ushort4(f2b(r2.x), f2b(r2.y), f2b(r2.z), f2b(r2.w));
    if (tid < 32) {
        const int i3 = 1536 + tid;
        *(ushort4*)&xs[i3 >> 5][(i3 & 31) << 2] =
            make_ushort4(f2b(r3.x), f2b(r3.y), f2b(r3.z), f2b(r3.w));
    }
}

__global__ __launch_bounds__(512, 6) void wattn_ws(
    const float* __restrict__ xg, const unsigned short* __restrict__ wb,
    const float* __restrict__ bb, const float* __restrict__ comb,
    float* __restrict__ outg)
{
    __shared__ SmemWS sm;
    const int tid  = threadIdx.x;
    const int lane = tid & 63;
    const int h    = (tid >> 6) & 3;   // head
    const int half = tid >> 8;         // m-half
    const int lr   = lane & 15;
    const int lq   = lane >> 4;
    const int bid  = blockIdx.x;

    // zero xs pad rows 49..63 once (stage_write only touches rows 0..48)
    if (tid < 480) {
        int idx = tid << 2;
        *(ushort4*)&sm.xs[49 + (idx >> 7)][idx & 127] = make_ushort4(0, 0, 0, 0);
    }

    // prologue: stage window bid
    float4 rg0 = {0,0,0,0}, rg1 = {0,0,0,0}, rg2 = {0,0,0,0}, rg3 = {0,0,0,0};
    stage_load(xg, bid, tid, rg0, rg1, rg2, rg3);
    stage_write(sm.xs, tid, rg0, rg1, rg2, rg3);

    const int s0x = lr + ((lq & 1) * 2) * 16;   // exchange source lanes
    const int s1x = s0x + 16;
    const bool hi = (lq >= 2);

    for (int w = bid; w < 4096; w += GRID_WS) {
        __syncthreads();               // bar A: xs holds window w

        // ---------------- af extraction ----------------
        bf16x8 af[4][2];
        #pragma unroll
        for (int ks = 0; ks < 4; ++ks)
            #pragma unroll
            for (int mtl = 0; mtl < 2; ++mtl)
                af[ks][mtl] = *(const bf16x8*)&sm.xs[(half * 2 + mtl) * 16 + lr][ks * 32 + lq * 8];

        // issue next window's x loads (drain after phase 2)
        const int wn = w + GRID_WS;
        if (wn < 4096) stage_load(xg, wn, tid, rg0, rg1, rg2, rg3);

        // ---- Q: swapped-operand MFMA -> Q^T in regs, exchange to qf fragments ----
        unsigned qfr[2][4];
        {
            f32x4 aq[2][2];   // [dhalf][mtl]
            #pragma unroll
            for (int dh = 0; dh < 2; ++dh) {
                const int cp = h * 32 + dh * 16 + lr;
                aq[dh][0] = f32x4{0.f, 0.f, 0.f, 0.f};
                aq[dh][1] = f32x4{0.f, 0.f, 0.f, 0.f};
                #pragma unroll
                for (int ks = 0; ks < 4; ++ks) {
                    bf16x8 wf = *(const bf16x8*)&wb[cp * 128 + ks * 32 + lq * 8];
                    aq[dh][0] = __builtin_amdgcn_mfma_f32_16x16x32_bf16(wf, af[ks][0], aq[dh][0], 0, 0, 0);
                    aq[dh][1] = __builtin_amdgcn_mfma_f32_16x16x32_bf16(wf, af[ks][1], aq[dh][1], 0, 0, 0);
                }
            }
            unsigned pq[2][2][2];
            #pragma unroll
            for (int dh = 0; dh < 2; ++dh) {
                const float4 qb = *(const float4*)&bb[h * 32 + dh * 16 + lq * 4];
                #pragma unroll
                for (int mtl = 0; mtl < 2; ++mtl) {
                    pq[dh][mtl][0] = pack2(aq[dh][mtl][0] + qb.x, aq[dh][mtl][1] + qb.y);
                    pq[dh][mtl][1] = pack2(aq[dh][mtl][2] + qb.z, aq[dh][mtl][3] + qb.w);
                }
            }
            #pragma unroll
            for (int bl = 0; bl < 2; ++bl) {
                unsigned a0 = (unsigned)__shfl((int)pq[0][bl][0], s0x);
                unsigned b0 = (unsigned)__shfl((int)pq[1][bl][0], s0x);
                unsigned a1 = (unsigned)__shfl((int)pq[0][bl][1], s0x);
                unsigned b1 = (unsigned)__shfl((int)pq[1][bl][1], s0x);
                unsigned a2 = (unsigned)__shfl((int)pq[0][bl][0], s1x);
                unsigned b2 = (unsigned)__shfl((int)pq[1][bl][0], s1x);
                unsigned a3 = (unsigned)__shfl((int)pq[0][bl][1], s1x);
                unsigned b3 = (unsigned)__shfl((int)pq[1][bl][1], s1x);
                qfr[bl][0] = hi ? b0 : a0;
                qfr[bl][1] = hi ? b1 : a1;
                qfr[bl][2] = hi ? b2 : a2;
                qfr[bl][3] = hi ? b3 : a3;
            }
        }

        // ---- K (s=1): normal MFMA -> LDS scatter ----
        #pragma unroll
        for (int dh = 0; dh < 2; ++dh) {
            const int cp = 128 + h * 32 + dh * 16 + lr;
            const int dd = dh * 16 + lr;
            const float bc = bb[cp];
            f32x4 acc[2];
            acc[0] = f32x4{0.f, 0.f, 0.f, 0.f};
            acc[1] = f32x4{0.f, 0.f, 0.f, 0.f};
            #pragma unroll
            for (int ks = 0; ks < 4; ++ks) {
                bf16x8 bf = *(const bf16x8*)&wb[cp * 128 + ks * 32 + lq * 8];
                #pragma unroll
                for (int mtl = 0; mtl < 2; ++mtl)
                    acc[mtl] = __builtin_amdgcn_mfma_f32_16x16x32_bf16(af[ks][mtl], bf, acc[mtl], 0, 0, 0);
            }
            #pragma unroll
            for (int mtl = 0; mtl < 2; ++mtl) {
                const int m0 = (half * 2 + mtl) * 16 + lq * 4;
                #pragma unroll
                for (int r = 0; r < 4; ++r)
                    sm.kk[h][m0 + r][dd] = f2b(acc[mtl][r] + bc);
            }
        }

        // ---- V (s=2): normal MFMA -> V^T store ----
        #pragma unroll
        for (int dh = 0; dh < 2; ++dh) {
            const int cp = 256 + h * 32 + dh * 16 + lr;
            const int dd = dh * 16 + lr;
            const float bc = bb[cp];
            f32x4 acc[2];
            acc[0] = f32x4{0.f, 0.f, 0.f, 0.f};
            acc[1] = f32x4{0.f, 0.f, 0.f, 0.f};
            #pragma unroll
            for (int ks = 0; ks < 4; ++ks) {
                bf16x8 bf = *(const bf16x8*)&wb[cp * 128 + ks * 32 + lq * 8];
                #pragma unroll
                for (int mtl = 0; mtl < 2; ++mtl)
                    acc[mtl] = __builtin_amdgcn_mfma_f32_16x16x32_bf16(af[ks][mtl], bf, acc[mtl], 0, 0, 0);
            }
            #pragma unroll
            for (int mtl = 0; mtl < 2; ++mtl) {
                const int m0 = (half * 2 + mtl) * 16 + lq * 4;
                *(ushort4*)&sm.vt[h][dd][m0] =
                    make_ushort4(f2b(acc[mtl][0] + bc), f2b(acc[mtl][1] + bc),
                                 f2b(acc[mtl][2] + bc), f2b(acc[mtl][3] + bc));
            }
        }
        __syncthreads();               // bar B: kk/vt ready; xs now dead

        // ---------------- phase 2: attention ----------------
        bf16x8 kf[4];
        #pragma unroll
        for (int t = 0; t < 4; ++t)
            kf[t] = *(const bf16x8*)&sm.kk[h][t * 16 + lr][lq * 8];

        const float* cwh = comb + (size_t)((w & 63) * 4 + h) * 3136;
        float* ob = outg + (size_t)w * 6272;
        const int src0 = ((lq & 1) * 2) * 16 + lr;
        const int src1 = src0 + 16;
        const bool up  = (lq >= 2);

        #pragma unroll
        for (int bl = 0; bl < 2; ++bl) {
            const int mt = half * 2 + bl;
            const int m  = mt * 16 + lr;
            const int mi = m < 48 ? m : 48;

            union { unsigned u[4]; bf16x8 v; } qu;
            qu.u[0] = qfr[bl][0]; qu.u[1] = qfr[bl][1];
            qu.u[2] = qfr[bl][2]; qu.u[3] = qfr[bl][3];

            const float* cr = cwh + mi * 64;
            f32x4 st[4];
            #pragma unroll
            for (int a = 0; a < 4; ++a) {
                f32x4 cc = *(const f32x4*)&cr[a * 16 + lq * 4];
                st[a] = __builtin_amdgcn_mfma_f32_16x16x32_bf16(kf[a], qu.v, cc, 0, 0, 0);
            }

            // softmax over row m (16 in-lane + lanes {lr, lr+16, lr+32, lr+48})
            float mx = -3.4e38f;
            #pragma unroll
            for (int a = 0; a < 4; ++a)
                #pragma unroll
                for (int r = 0; r < 4; ++r) mx = fmaxf(mx, st[a][r]);
            mx = fmaxf(mx, __shfl_xor(mx, 16));
            mx = fmaxf(mx, __shfl_xor(mx, 32));
            float sum = 0.f;
            #pragma unroll
            for (int a = 0; a < 4; ++a)
                #pragma unroll
                for (int r = 0; r < 4; ++r) {
                    float e = __expf(st[a][r] - mx);
                    st[a][r] = e;
                    sum += e;
                }
            sum += __shfl_xor(sum, 16);
            sum += __shfl_xor(sum, 32);
            const float inv = 1.f / sum;

            unsigned pk[4][2];
            #pragma unroll
            for (int a = 0; a < 4; ++a) {
                pk[a][0] = pack2(st[a][0] * inv, st[a][1] * inv);
                pk[a][1] = pack2(st[a][2] * inv, st[a][3] * inv);
            }

            // PV: out^T[d][m] = sum_n Vt[d][n] * P[m][n]
            f32x4 o[2];
            o[0] = f32x4{0.f, 0.f, 0.f, 0.f};
            o[1] = f32x4{0.f, 0.f, 0.f, 0.f};
            #pragma unroll
            for (int kt = 0; kt < 2; ++kt) {
                unsigned ea0 = (unsigned)__shfl((int)pk[2 * kt][0], src0);
                unsigned ea1 = (unsigned)__shfl((int)pk[2 * kt][1], src0);
                unsigned ea2 = (unsigned)__shfl((int)pk[2 * kt][0], src1);
                unsigned ea3 = (unsigned)__shfl((int)pk[2 * kt][1], src1);
                unsigned eb0 = (unsigned)__shfl((int)pk[2 * kt + 1][0], src0);
                unsigned eb1 = (unsigned)__shfl((int)pk[2 * kt + 1][1], src0);
                unsigned eb2 = (unsigned)__shfl((int)pk[2 * kt + 1][0], src1);
                unsigned eb3 = (unsigned)__shfl((int)pk[2 * kt + 1][1], src1);
                union { unsigned u[4]; bf16x8 v; } pu;
                pu.u[0] = up ? eb0 : ea0;
                pu.u[1] = up ? eb1 : ea1;
                pu.u[2] = up ? eb2 : ea2;
                pu.u[3] = up ? eb3 : ea3;
                #pragma unroll
                for (int dt = 0; dt < 2; ++dt) {
                    bf16x8 vf = *(const bf16x8*)&sm.vt[h][dt * 16 + lr][kt * 32 + lq * 8];
                    o[dt] = __builtin_amdgcn_mfma_f32_16x16x32_bf16(vf, pu.v, o[dt], 0, 0, 0);
                }
            }

            if (m < 49) {
                #pragma unroll
                for (int dt = 0; dt < 2; ++dt) {
                    float4 v = make_float4(o[dt][0], o[dt][1], o[dt][2], o[dt][3]);
                    *(float4*)&ob[m * 128 + h * 32 + dt * 16 + lq * 4] = v;
                }
            }
        }

        // stage next window's x into xs (loads drained here, after phase 2)
        if (wn < 4096) stage_write(sm.xs, tid, rg0, rg1, rg2, rg3);
    }
}

// ---------------- fallback kernel (no workspace): R3/R6-proven path ----------------
struct __align__(16) SmemFB {
    unsigned short qk[2][4][64][32];
    union {
        unsigned short xs[64][136];
        unsigned short vt[4][32][72];
    } b;
};

__global__ __launch_bounds__(512, 6) void wattn_fb(
    const float* __restrict__ xg, const float* __restrict__ maskg,
    const float* __restrict__ qkvw, const float* __restrict__ qkvb,
    const float* __restrict__ relt, float* __restrict__ outg)
{
    __shared__ SmemFB sm;
    const int tid  = threadIdx.x;
    const int lane = tid & 63;
    const int wv   = tid >> 6;
    const int h    = wv & 3;
    const int half = wv >> 2;
    const int lr   = lane & 15;
    const int lq   = lane >> 4;
    const int bI   = blockIdx.x;

    const float* xb = xg + (size_t)bI * 6272;
    #pragma unroll
    for (int it = 0; it < 4; ++it) {
        int i = it * 512 + tid;
        if (i < 1568) {
            float4 v = ((const float4*)xb)[i];
            int row = i >> 5, col = (i & 31) << 2;
            *(ushort4*)&sm.b.xs[row][col] =
                make_ushort4(f2b(v.x), f2b(v.y), f2b(v.z), f2b(v.w));
        }
    }
    if (tid < 480) {
        int idx = tid << 2;
        *(ushort4*)&sm.b.xs[49 + (idx >> 7)][idx & 127] = make_ushort4(0, 0, 0, 0);
    }
    __syncthreads();

    bf16x8 af[4][2];
    #pragma unroll
    for (int ks = 0; ks < 4; ++ks)
        #pragma unroll
        for (int mtl = 0; mtl < 2; ++mtl)
            af[ks][mtl] = *(const bf16x8*)&sm.b.xs[(half * 2 + mtl) * 16 + lr][ks * 32 + lq * 8];
    __syncthreads();

    unsigned short* sbase = (unsigned short*)&sm;
    #pragma unroll
    for (int j = 0; j < 6; ++j) {
        const int c = (h * 6 + j) * 16 + lr;
        const float bc = qkvb[c];
        const int rem = j * 16 + lr;
        const int dd = rem / 3, s = rem % 3;
        const float mulv = (s == 0) ? 0.17677669529663687f : 1.0f;
        f32x4 acc[2];
        acc[0] = f32x4{0.f, 0.f, 0.f, 0.f};
        acc[1] = f32x4{0.f, 0.f, 0.f, 0.f};
        #pragma unroll
        for (int ks = 0; ks < 4; ++ks) {
            const float4* wp = (const float4*)(qkvw + c * 128 + ks * 32 + lq * 8);
            float4 w0 = wp[0], w1 = wp[1];
            bf16x8 t;
            t[0] = (short)f2b(w0.x); t[1] = (short)f2b(w0.y);
            t[2] = (short)f2b(w0.z); t[3] = (short)f2b(w0.w);
            t[4] = (short)f2b(w1.x); t[5] = (short)f2b(w1.y);
            t[6] = (short)f2b(w1.z); t[7] = (short)f2b(w1.w);
            #pragma unroll
            for (int mtl = 0; mtl < 2; ++mtl)
                acc[mtl] = __builtin_amdgcn_mfma_f32_16x16x32_bf16(af[ks][mtl], t, acc[mtl], 0, 0, 0);
        }
        #pragma unroll
        for (int mtl = 0; mtl < 2; ++mtl)
            #pragma unroll
            for (int r = 0; r < 4; ++r) {
                int m = (half * 2 + mtl) * 16 + lq * 4 + r;
                int soff = (s == 2) ? (16384 + (h * 32 + dd) * 72 + m)
                                    : (s * 8192 + h * 2048 + m * 32 + dd);
                sbase[soff] = f2b((acc[mtl][r] + bc) * mulv);
            }
    }
    __syncthreads();

    bf16x8 kf[4];
    #pragma unroll
    for (int t = 0; t < 4; ++t)
        kf[t] = *(const bf16x8*)&sm.qk[1][h][t * 16 + lr][lq * 8];

    const float* mw = maskg + (size_t)(bI & 63) * 2401;
    float* ob = outg + (size_t)bI * 6272;
    const int src0 = ((lq & 1) * 2) * 16 + lr;
    const int src1 = src0 + 16;
    const bool up  = (lq >= 2);

    #pragma unroll
    for (int bl = 0; bl < 2; ++bl) {
        const int mt = half * 2 + bl;
        const int m  = mt * 16 + lr;
        const int mi = m < 48 ? m : 48;

        f32x4 st[4];
        bf16x8 qf = *(const bf16x8*)&sm.qk[0][h][m][lq * 8];
        #pragma unroll
        for (int a = 0; a < 4; ++a) {
            f32x4 z = f32x4{0.f, 0.f, 0.f, 0.f};
            st[a] = __builtin_amdgcn_mfma_f32_16x16x32_bf16(kf[a], qf, z, 0, 0, 0);
        }
        const int md = mi / 7, mm = mi - md * 7;
        #pragma unroll
        for (int a = 0; a < 4; ++a)
            #pragma unroll
            for (int r = 0; r < 4; ++r) {
                int n = a * 16 + lq * 4 + r;
                int ni = n < 48 ? n : 48;
                int nd = ni / 7, nm = ni - nd * 7;
                int ridx = (md - nd + 6) * 13 + (mm - nm + 6);
                float v = st[a][r] + relt[ridx * 4 + h] + mw[mi * 49 + ni];
                st[a][r] = (n < 49) ? v : -1e30f;
            }

        float mx = -3.4e38f;
        #pragma unroll
        for (int a = 0; a < 4; ++a)
            #pragma unroll
            for (int r = 0; r < 4; ++r) mx = fmaxf(mx, st[a][r]);
        mx = fmaxf(mx, __shfl_xor(mx, 16));
        mx = fmaxf(mx, __shfl_xor(mx, 32));
        float sum = 0.f;
        #pragma unroll
        for (int a = 0; a < 4; ++a)
            #pragma unroll
            for (int r = 0; r < 4; ++r) {
                float e = __expf(st[a][r] - mx);
                st[a][r] = e;
                sum += e;
            }
        sum += __shfl_xor(sum, 16);
        sum += __shfl_xor(sum, 32);
        const float inv = 1.f / sum;

        unsigned pk[4][2];
        #pragma unroll
        for (int a = 0; a < 4; ++a) {
            pk[a][0] = pack2(st[a][0] * inv, st[a][1] * inv);
            pk[a][1] = pack2(st[a][2] * inv, st[a][3] * inv);
        }

        f32x4 o[2];
        o[0] = f32x4{0.f, 0.f, 0.f, 0.f};
        o[1] = f32x4{0.f, 0.f, 0.f, 0.f};
        #pragma unroll
        for (int kt = 0; kt < 2; ++kt) {
            unsigned ea0 = (unsigned)__shfl((int)pk[2 * kt][0], src0);
            unsigned ea1 = (unsigned)__shfl((int)pk[2 * kt][1], src0);
            unsigned ea2 = (unsigned)__shfl((int)pk[2 * kt][0], src1);
            unsigned ea3 = (unsigned)__shfl((int)pk[2 * kt][1], src1);
            unsigned eb0 = (unsigned)__shfl((int)pk[2 * kt + 1][0], src0);
            unsigned eb1 = (unsigned)__shfl((int)pk[2 * kt + 1][1], src0);
            unsigned eb2 = (unsigned)__shfl((int)pk[2 * kt + 1][0], src1);
            unsigned eb3 = (unsigned)__shfl((int)pk[2 * kt + 1][1], src1);
            union { unsigned u[4]; bf16x8 v; } pu;
            pu.u[0] = up ? eb0 : ea0;
            pu.u[1] = up ? eb1 : ea1;
            pu.u[2] = up ? eb2 : ea2;
            pu.u[3] = up ? eb3 : ea3;
            #pragma unroll
            for (int dt = 0; dt < 2; ++dt) {
                bf16x8 vf = *(const bf16x8*)&sm.b.vt[h][dt * 16 + lr][kt * 32 + lq * 8];
                o[dt] = __builtin_amdgcn_mfma_f32_16x16x32_bf16(vf, pu.v, o[dt], 0, 0, 0);
            }
        }

        if (m < 49) {
            #pragma unroll
            for (int dt = 0; dt < 2; ++dt) {
                float4 v = make_float4(o[dt][0], o[dt][1], o[dt][2], o[dt][3]);
                *(float4*)&ob[m * 128 + h * 32 + dt * 16 + lq * 4] = v;
            }
        }
    }
}

extern "C" void kernel_launch(void* const* d_in, const int* in_sizes, int n_in,
                              void* d_out, int out_size, void* d_ws, size_t ws_size,
                              hipStream_t stream) {
    const float* x    = (const float*)d_in[0];
    const float* mask = (const float*)d_in[1];
    const float* qkvw = (const float*)d_in[2];
    const float* qkvb = (const float*)d_in[3];
    const float* relt = (const float*)d_in[4];
    float* out = (float*)d_out;

    if (d_ws != nullptr && ws_size >= (size_t)WS_NEED) {
        unsigned short* wbf = (unsigned short*)d_ws;
        float* bbf  = (float*)((char*)d_ws + WS_BIAS_OFF);
        float* comb = (float*)((char*)d_ws + WS_COMB_OFF);
        prep_kernel<<<3330, 256, 0, stream>>>(qkvw, qkvb, mask, relt, wbf, bbf, comb);
        wattn_ws<<<GRID_WS, 512, 0, stream>>>(x, wbf, bbf, comb, out);
    } else {
        wattn_fb<<<4096, 512, 0, stream>>>(x, mask, qkvw, qkvb, relt, out);
    }
}

// Round 9
// 332.159 us; speedup vs baseline: 1.4645x; 1.4645x over previous
//
#include <hip/hip_runtime.h>

// WindowAttention: B_=4096 windows, N=49, DIM=128, NH=4, HD=32, nW=64.
// 512 threads = 8 waves; wave w -> (head = w&3, m-half = w>>2).
// bf16 MFMA 16x16x32. S computed transposed (S^T = K*Q^T): softmax rows in-lane,
// P feeds PV as B-fragment via shuffles. Q never touches LDS (R7-verified
// swapped-MFMA + in-wave exchange).
// R9 = R8 persistent pipeline, spill fixed via launch_bounds(512,4):
//  - R5/R8 established: at (512,6) the unified VGPR+AGPR budget (~85/wave) has
//    zero headroom; any >=16 extra live regs across MFMA phases -> scratch
//    spill (R8: WRITE 445 MB, FETCH 632 MB, MfmaUtil 3.8%).
//  - (512,4) -> 128 regs/wave (est. peak ~110, no spill), worst case
//    2 blocks/CU (16 waves). Trades 1/3 of TLP for the ILP to run the
//    cross-window prefetch legally.
//  - grid 512 (2/CU), 8 windows/block exactly; x for window w+512 loaded to
//    regs during window w's compute, written to xs after phase 2.
//  - weights/comb become L1/L2-hot after each block's first window (reused 8x).
// Tripwires: WRITE_SIZE >> 100 MB = spill (revert to R6); Occupancy ~50%.

typedef short bf16x8 __attribute__((ext_vector_type(8)));
typedef float f32x4 __attribute__((ext_vector_type(4)));

#define DEVI __device__ __forceinline__

DEVI unsigned short f2b(float f) {   // fp32 -> bf16 bits, round-to-nearest-even
    unsigned u = __builtin_bit_cast(unsigned, f);
    u += 0x7fffu + ((u >> 16) & 1u);
    return (unsigned short)(u >> 16);
}

DEVI unsigned pack2(float lo, float hi) {
    return (unsigned)f2b(lo) | ((unsigned)f2b(hi) << 16);
}

#define WS_BIAS_OFF 98304
#define WS_COMB_OFF 131072
#define COMB_ELEMS  802816u   // 256 * 49 * 64 (padded n-dim to 64)
#define WS_NEED     (131072u + COMB_ELEMS * 4u)
#define GRID_WS     512

__global__ __launch_bounds__(256) void prep_kernel(
    const float* __restrict__ qkvw, const float* __restrict__ qkvb,
    const float* __restrict__ maskg, const float* __restrict__ relt,
    unsigned short* __restrict__ wb, float* __restrict__ bb,
    float* __restrict__ comb)
{
    const int g = blockIdx.x * 256 + threadIdx.x;
    if (g < 49152) {
        const int row = g >> 7, col = g & 127;
        const int s = row >> 7, r7 = row & 127, hh = r7 >> 5, d = r7 & 31;
        const int c = hh * 96 + d * 3 + s;          // torch row
        const float mul = (s == 0) ? 0.17677669529663687f : 1.0f;
        wb[row * 128 + col] = f2b(qkvw[c * 128 + col] * mul);
    } else if (g < 49536) {
        const int row = g - 49152;
        const int s = row >> 7, r7 = row & 127, hh = r7 >> 5, d = r7 & 31;
        const int c = hh * 96 + d * 3 + s;
        const float mul = (s == 0) ? 0.17677669529663687f : 1.0f;
        bb[row] = qkvb[c] * mul;
    } else {
        const unsigned g2 = (unsigned)(g - 49536);
        if (g2 < COMB_ELEMS) {
            const int wh = g2 / 3136;
            const int rr = g2 - wh * 3136;
            const int m = rr >> 6, n = rr & 63;
            const int w = wh >> 2, hh = wh & 3;
            float v = -1e30f;
            if (n < 49) {
                const int md = m / 7, mm = m - md * 7;
                const int nd = n / 7, nm = n - nd * 7;
                const int ridx = (md - nd + 6) * 13 + (mm - nm + 6);
                v = maskg[w * 2401 + m * 49 + n] + relt[ridx * 4 + hh];
            }
            comb[g2] = v;
        }
    }
}

// ---------------- workspace (fast) kernel ----------------
// LDS: kk 16384 + vt 18432 + xs 17408 = 52224 B.
struct __align__(16) SmemWS {
    unsigned short kk[4][64][32];      // K [head][n][d]
    unsigned short vt[4][32][72];      // V^T [head][d][n], 144 B rows
    unsigned short xs[64][136];        // staged x, 272 B rows
};

DEVI void stage_load(const float* __restrict__ xg, int w, int tid,
                     float4& r0, float4& r1, float4& r2, float4& r3) {
    const float4* xb = (const float4*)(xg + (size_t)w * 6272);
    r0 = xb[tid];
    r1 = xb[512 + tid];
    r2 = xb[1024 + tid];
    if (tid < 32) r3 = xb[1536 + tid];
}

DEVI void stage_write(unsigned short (*xs)[136], int tid,
                      const float4& r0, const float4& r1,
                      const float4& r2, const float4& r3) {
    const int i0 = tid, i1 = 512 + tid, i2 = 1024 + tid;
    *(ushort4*)&xs[i0 >> 5][(i0 & 31) << 2] =
        make_ushort4(f2b(r0.x), f2b(r0.y), f2b(r0.z), f2b(r0.w));
    *(ushort4*)&xs[i1 >> 5][(i1 & 31) << 2] =
        make_ushort4(f2b(r1.x), f2b(r1.y), f2b(r1.z), f2b(r1.w));
    *(ushort4*)&xs[i2 >> 5][(i2 & 31) << 2] =
        make_ushort4(f2b(r2.x), f2b(r2.y), f2b(r2.z), f2b(r2.w));
    if (tid < 32) {
        const int i3 = 1536 + tid;
        *(ushort4*)&xs[i3 >> 5][(i3 & 31) << 2] =
            make_ushort4(f2b(r3.x), f2b(r3.y), f2b(r3.z), f2b(r3.w));
    }
}

__global__ __launch_bounds__(512, 4) void wattn_ws(
    const float* __restrict__ xg, const unsigned short* __restrict__ wb,
    const float* __restrict__ bb, const float* __restrict__ comb,
    float* __restrict__ outg)
{
    __shared__ SmemWS sm;
    const int tid  = threadIdx.x;
    const int lane = tid & 63;
    const int h    = (tid >> 6) & 3;   // head
    const int half = tid >> 8;         // m-half
    const int lr   = lane & 15;
    const int lq   = lane >> 4;
    const int bid  = blockIdx.x;

    // zero xs pad rows 49..63 once (stage_write only touches rows 0..48)
    if (tid < 480) {
        int idx = tid << 2;
        *(ushort4*)&sm.xs[49 + (idx >> 7)][idx & 127] = make_ushort4(0, 0, 0, 0);
    }

    // prologue: stage window bid
    float4 rg0 = {0,0,0,0}, rg1 = {0,0,0,0}, rg2 = {0,0,0,0}, rg3 = {0,0,0,0};
    stage_load(xg, bid, tid, rg0, rg1, rg2, rg3);
    stage_write(sm.xs, tid, rg0, rg1, rg2, rg3);

    const int s0x = lr + ((lq & 1) * 2) * 16;   // exchange source lanes
    const int s1x = s0x + 16;
    const bool hi = (lq >= 2);

    for (int w = bid; w < 4096; w += GRID_WS) {
        __syncthreads();               // bar A: xs holds window w

        // ---------------- af extraction ----------------
        bf16x8 af[4][2];
        #pragma unroll
        for (int ks = 0; ks < 4; ++ks)
            #pragma unroll
            for (int mtl = 0; mtl < 2; ++mtl)
                af[ks][mtl] = *(const bf16x8*)&sm.xs[(half * 2 + mtl) * 16 + lr][ks * 32 + lq * 8];

        // issue next window's x loads (drain after phase 2)
        const int wn = w + GRID_WS;
        if (wn < 4096) stage_load(xg, wn, tid, rg0, rg1, rg2, rg3);

        // ---- Q: swapped-operand MFMA -> Q^T in regs, exchange to qf fragments ----
        unsigned qfr[2][4];
        {
            f32x4 aq[2][2];   // [dhalf][mtl]
            #pragma unroll
            for (int dh = 0; dh < 2; ++dh) {
                const int cp = h * 32 + dh * 16 + lr;
                aq[dh][0] = f32x4{0.f, 0.f, 0.f, 0.f};
                aq[dh][1] = f32x4{0.f, 0.f, 0.f, 0.f};
                #pragma unroll
                for (int ks = 0; ks < 4; ++ks) {
                    bf16x8 wf = *(const bf16x8*)&wb[cp * 128 + ks * 32 + lq * 8];
                    aq[dh][0] = __builtin_amdgcn_mfma_f32_16x16x32_bf16(wf, af[ks][0], aq[dh][0], 0, 0, 0);
                    aq[dh][1] = __builtin_amdgcn_mfma_f32_16x16x32_bf16(wf, af[ks][1], aq[dh][1], 0, 0, 0);
                }
            }
            unsigned pq[2][2][2];
            #pragma unroll
            for (int dh = 0; dh < 2; ++dh) {
                const float4 qb = *(const float4*)&bb[h * 32 + dh * 16 + lq * 4];
                #pragma unroll
                for (int mtl = 0; mtl < 2; ++mtl) {
                    pq[dh][mtl][0] = pack2(aq[dh][mtl][0] + qb.x, aq[dh][mtl][1] + qb.y);
                    pq[dh][mtl][1] = pack2(aq[dh][mtl][2] + qb.z, aq[dh][mtl][3] + qb.w);
                }
            }
            #pragma unroll
            for (int bl = 0; bl < 2; ++bl) {
                unsigned a0 = (unsigned)__shfl((int)pq[0][bl][0], s0x);
                unsigned b0 = (unsigned)__shfl((int)pq[1][bl][0], s0x);
                unsigned a1 = (unsigned)__shfl((int)pq[0][bl][1], s0x);
                unsigned b1 = (unsigned)__shfl((int)pq[1][bl][1], s0x);
                unsigned a2 = (unsigned)__shfl((int)pq[0][bl][0], s1x);
                unsigned b2 = (unsigned)__shfl((int)pq[1][bl][0], s1x);
                unsigned a3 = (unsigned)__shfl((int)pq[0][bl][1], s1x);
                unsigned b3 = (unsigned)__shfl((int)pq[1][bl][1], s1x);
                qfr[bl][0] = hi ? b0 : a0;
                qfr[bl][1] = hi ? b1 : a1;
                qfr[bl][2] = hi ? b2 : a2;
                qfr[bl][3] = hi ? b3 : a3;
            }
        }

        // ---- K (s=1): normal MFMA -> LDS scatter ----
        #pragma unroll
        for (int dh = 0; dh < 2; ++dh) {
            const int cp = 128 + h * 32 + dh * 16 + lr;
            const int dd = dh * 16 + lr;
            const float bc = bb[cp];
            f32x4 acc[2];
            acc[0] = f32x4{0.f, 0.f, 0.f, 0.f};
            acc[1] = f32x4{0.f, 0.f, 0.f, 0.f};
            #pragma unroll
            for (int ks = 0; ks < 4; ++ks) {
                bf16x8 bf = *(const bf16x8*)&wb[cp * 128 + ks * 32 + lq * 8];
                #pragma unroll
                for (int mtl = 0; mtl < 2; ++mtl)
                    acc[mtl] = __builtin_amdgcn_mfma_f32_16x16x32_bf16(af[ks][mtl], bf, acc[mtl], 0, 0, 0);
            }
            #pragma unroll
            for (int mtl = 0; mtl < 2; ++mtl) {
                const int m0 = (half * 2 + mtl) * 16 + lq * 4;
                #pragma unroll
                for (int r = 0; r < 4; ++r)
                    sm.kk[h][m0 + r][dd] = f2b(acc[mtl][r] + bc);
            }
        }

        // ---- V (s=2): normal MFMA -> V^T store ----
        #pragma unroll
        for (int dh = 0; dh < 2; ++dh) {
            const int cp = 256 + h * 32 + dh * 16 + lr;
            const int dd = dh * 16 + lr;
            const float bc = bb[cp];
            f32x4 acc[2];
            acc[0] = f32x4{0.f, 0.f, 0.f, 0.f};
            acc[1] = f32x4{0.f, 0.f, 0.f, 0.f};
            #pragma unroll
            for (int ks = 0; ks < 4; ++ks) {
                bf16x8 bf = *(const bf16x8*)&wb[cp * 128 + ks * 32 + lq * 8];
                #pragma unroll
                for (int mtl = 0; mtl < 2; ++mtl)
                    acc[mtl] = __builtin_amdgcn_mfma_f32_16x16x32_bf16(af[ks][mtl], bf, acc[mtl], 0, 0, 0);
            }
            #pragma unroll
            for (int mtl = 0; mtl < 2; ++mtl) {
                const int m0 = (half * 2 + mtl) * 16 + lq * 4;
                *(ushort4*)&sm.vt[h][dd][m0] =
                    make_ushort4(f2b(acc[mtl][0] + bc), f2b(acc[mtl][1] + bc),
                                 f2b(acc[mtl][2] + bc), f2b(acc[mtl][3] + bc));
            }
        }
        __syncthreads();               // bar B: kk/vt ready; xs now dead

        // ---------------- phase 2: attention ----------------
        bf16x8 kf[4];
        #pragma unroll
        for (int t = 0; t < 4; ++t)
            kf[t] = *(const bf16x8*)&sm.kk[h][t * 16 + lr][lq * 8];

        const float* cwh = comb + (size_t)((w & 63) * 4 + h) * 3136;
        float* ob = outg + (size_t)w * 6272;
        const int src0 = ((lq & 1) * 2) * 16 + lr;
        const int src1 = src0 + 16;
        const bool up  = (lq >= 2);

        #pragma unroll
        for (int bl = 0; bl < 2; ++bl) {
            const int mt = half * 2 + bl;
            const int m  = mt * 16 + lr;
            const int mi = m < 48 ? m : 48;

            union { unsigned u[4]; bf16x8 v; } qu;
            qu.u[0] = qfr[bl][0]; qu.u[1] = qfr[bl][1];
            qu.u[2] = qfr[bl][2]; qu.u[3] = qfr[bl][3];

            const float* cr = cwh + mi * 64;
            f32x4 st[4];
            #pragma unroll
            for (int a = 0; a < 4; ++a) {
                f32x4 cc = *(const f32x4*)&cr[a * 16 + lq * 4];
                st[a] = __builtin_amdgcn_mfma_f32_16x16x32_bf16(kf[a], qu.v, cc, 0, 0, 0);
            }

            // softmax over row m (16 in-lane + lanes {lr, lr+16, lr+32, lr+48})
            float mx = -3.4e38f;
            #pragma unroll
            for (int a = 0; a < 4; ++a)
                #pragma unroll
                for (int r = 0; r < 4; ++r) mx = fmaxf(mx, st[a][r]);
            mx = fmaxf(mx, __shfl_xor(mx, 16));
            mx = fmaxf(mx, __shfl_xor(mx, 32));
            float sum = 0.f;
            #pragma unroll
            for (int a = 0; a < 4; ++a)
                #pragma unroll
                for (int r = 0; r < 4; ++r) {
                    float e = __expf(st[a][r] - mx);
                    st[a][r] = e;
                    sum += e;
                }
            sum += __shfl_xor(sum, 16);
            sum += __shfl_xor(sum, 32);
            const float inv = 1.f / sum;

            unsigned pk[4][2];
            #pragma unroll
            for (int a = 0; a < 4; ++a) {
                pk[a][0] = pack2(st[a][0] * inv, st[a][1] * inv);
                pk[a][1] = pack2(st[a][2] * inv, st[a][3] * inv);
            }

            // PV: out^T[d][m] = sum_n Vt[d][n] * P[m][n]
            f32x4 o[2];
            o[0] = f32x4{0.f, 0.f, 0.f, 0.f};
            o[1] = f32x4{0.f, 0.f, 0.f, 0.f};
            #pragma unroll
            for (int kt = 0; kt < 2; ++kt) {
                unsigned ea0 = (unsigned)__shfl((int)pk[2 * kt][0], src0);
                unsigned ea1 = (unsigned)__shfl((int)pk[2 * kt][1], src0);
                unsigned ea2 = (unsigned)__shfl((int)pk[2 * kt][0], src1);
                unsigned ea3 = (unsigned)__shfl((int)pk[2 * kt][1], src1);
                unsigned eb0 = (unsigned)__shfl((int)pk[2 * kt + 1][0], src0);
                unsigned eb1 = (unsigned)__shfl((int)pk[2 * kt + 1][1], src0);
                unsigned eb2 = (unsigned)__shfl((int)pk[2 * kt + 1][0], src1);
                unsigned eb3 = (unsigned)__shfl((int)pk[2 * kt + 1][1], src1);
                union { unsigned u[4]; bf16x8 v; } pu;
                pu.u[0] = up ? eb0 : ea0;
                pu.u[1] = up ? eb1 : ea1;
                pu.u[2] = up ? eb2 : ea2;
                pu.u[3] = up ? eb3 : ea3;
                #pragma unroll
                for (int dt = 0; dt < 2; ++dt) {
                    bf16x8 vf = *(const bf16x8*)&sm.vt[h][dt * 16 + lr][kt * 32 + lq * 8];
                    o[dt] = __builtin_amdgcn_mfma_f32_16x16x32_bf16(vf, pu.v, o[dt], 0, 0, 0);
                }
            }

            if (m < 49) {
                #pragma unroll
                for (int dt = 0; dt < 2; ++dt) {
                    float4 v = make_float4(o[dt][0], o[dt][1], o[dt][2], o[dt][3]);
                    *(float4*)&ob[m * 128 + h * 32 + dt * 16 + lq * 4] = v;
                }
            }
        }

        // stage next window's x into xs (loads drained here, after phase 2)
        if (wn < 4096) stage_write(sm.xs, tid, rg0, rg1, rg2, rg3);
    }
}

// ---------------- fallback kernel (no workspace): R3/R6-proven path ----------------
struct __align__(16) SmemFB {
    unsigned short qk[2][4][64][32];
    union {
        unsigned short xs[64][136];
        unsigned short vt[4][32][72];
    } b;
};

__global__ __launch_bounds__(512, 6) void wattn_fb(
    const float* __restrict__ xg, const float* __restrict__ maskg,
    const float* __restrict__ qkvw, const float* __restrict__ qkvb,
    const float* __restrict__ relt, float* __restrict__ outg)
{
    __shared__ SmemFB sm;
    const int tid  = threadIdx.x;
    const int lane = tid & 63;
    const int wv   = tid >> 6;
    const int h    = wv & 3;
    const int half = wv >> 2;
    const int lr   = lane & 15;
    const int lq   = lane >> 4;
    const int bI   = blockIdx.x;

    const float* xb = xg + (size_t)bI * 6272;
    #pragma unroll
    for (int it = 0; it < 4; ++it) {
        int i = it * 512 + tid;
        if (i < 1568) {
            float4 v = ((const float4*)xb)[i];
            int row = i >> 5, col = (i & 31) << 2;
            *(ushort4*)&sm.b.xs[row][col] =
                make_ushort4(f2b(v.x), f2b(v.y), f2b(v.z), f2b(v.w));
        }
    }
    if (tid < 480) {
        int idx = tid << 2;
        *(ushort4*)&sm.b.xs[49 + (idx >> 7)][idx & 127] = make_ushort4(0, 0, 0, 0);
    }
    __syncthreads();

    bf16x8 af[4][2];
    #pragma unroll
    for (int ks = 0; ks < 4; ++ks)
        #pragma unroll
        for (int mtl = 0; mtl < 2; ++mtl)
            af[ks][mtl] = *(const bf16x8*)&sm.b.xs[(half * 2 + mtl) * 16 + lr][ks * 32 + lq * 8];
    __syncthreads();

    unsigned short* sbase = (unsigned short*)&sm;
    #pragma unroll
    for (int j = 0; j < 6; ++j) {
        const int c = (h * 6 + j) * 16 + lr;
        const float bc = qkvb[c];
        const int rem = j * 16 + lr;
        const int dd = rem / 3, s = rem % 3;
        const float mulv = (s == 0) ? 0.17677669529663687f : 1.0f;
        f32x4 acc[2];
        acc[0] = f32x4{0.f, 0.f, 0.f, 0.f};
        acc[1] = f32x4{0.f, 0.f, 0.f, 0.f};
        #pragma unroll
        for (int ks = 0; ks < 4; ++ks) {
            const float4* wp = (const float4*)(qkvw + c * 128 + ks * 32 + lq * 8);
            float4 w0 = wp[0], w1 = wp[1];
            bf16x8 t;
            t[0] = (short)f2b(w0.x); t[1] = (short)f2b(w0.y);
            t[2] = (short)f2b(w0.z); t[3] = (short)f2b(w0.w);
            t[4] = (short)f2b(w1.x); t[5] = (short)f2b(w1.y);
            t[6] = (short)f2b(w1.z); t[7] = (short)f2b(w1.w);
            #pragma unroll
            for (int mtl = 0; mtl < 2; ++mtl)
                acc[mtl] = __builtin_amdgcn_mfma_f32_16x16x32_bf16(af[ks][mtl], t, acc[mtl], 0, 0, 0);
        }
        #pragma unroll
        for (int mtl = 0; mtl < 2; ++mtl)
            #pragma unroll
            for (int r = 0; r < 4; ++r) {
                int m = (half * 2 + mtl) * 16 + lq * 4 + r;
                int soff = (s == 2) ? (16384 + (h * 32 + dd) * 72 + m)
                                    : (s * 8192 + h * 2048 + m * 32 + dd);
                sbase[soff] = f2b((acc[mtl][r] + bc) * mulv);
            }
    }
    __syncthreads();

    bf16x8 kf[4];
    #pragma unroll
    for (int t = 0; t < 4; ++t)
        kf[t] = *(const bf16x8*)&sm.qk[1][h][t * 16 + lr][lq * 8];

    const float* mw = maskg + (size_t)(bI & 63) * 2401;
    float* ob = outg + (size_t)bI * 6272;
    const int src0 = ((lq & 1) * 2) * 16 + lr;
    const int src1 = src0 + 16;
    const bool up  = (lq >= 2);

    #pragma unroll
    for (int bl = 0; bl < 2; ++bl) {
        const int mt = half * 2 + bl;
        const int m  = mt * 16 + lr;
        const int mi = m < 48 ? m : 48;

        f32x4 st[4];
        bf16x8 qf = *(const bf16x8*)&sm.qk[0][h][m][lq * 8];
        #pragma unroll
        for (int a = 0; a < 4; ++a) {
            f32x4 z = f32x4{0.f, 0.f, 0.f, 0.f};
            st[a] = __builtin_amdgcn_mfma_f32_16x16x32_bf16(kf[a], qf, z, 0, 0, 0);
        }
        const int md = mi / 7, mm = mi - md * 7;
        #pragma unroll
        for (int a = 0; a < 4; ++a)
            #pragma unroll
            for (int r = 0; r < 4; ++r) {
                int n = a * 16 + lq * 4 + r;
                int ni = n < 48 ? n : 48;
                int nd = ni / 7, nm = ni - nd * 7;
                int ridx = (md - nd + 6) * 13 + (mm - nm + 6);
                float v = st[a][r] + relt[ridx * 4 + h] + mw[mi * 49 + ni];
                st[a][r] = (n < 49) ? v : -1e30f;
            }

        float mx = -3.4e38f;
        #pragma unroll
        for (int a = 0; a < 4; ++a)
            #pragma unroll
            for (int r = 0; r < 4; ++r) mx = fmaxf(mx, st[a][r]);
        mx = fmaxf(mx, __shfl_xor(mx, 16));
        mx = fmaxf(mx, __shfl_xor(mx, 32));
        float sum = 0.f;
        #pragma unroll
        for (int a = 0; a < 4; ++a)
            #pragma unroll
            for (int r = 0; r < 4; ++r) {
                float e = __expf(st[a][r] - mx);
                st[a][r] = e;
                sum += e;
            }
        sum += __shfl_xor(sum, 16);
        sum += __shfl_xor(sum, 32);
        const float inv = 1.f / sum;

        unsigned pk[4][2];
        #pragma unroll
        for (int a = 0; a < 4; ++a) {
            pk[a][0] = pack2(st[a][0] * inv, st[a][1] * inv);
            pk[a][1] = pack2(st[a][2] * inv, st[a][3] * inv);
        }

        f32x4 o[2];
        o[0] = f32x4{0.f, 0.f, 0.f, 0.f};
        o[1] = f32x4{0.f, 0.f, 0.f, 0.f};
        #pragma unroll
        for (int kt = 0; kt < 2; ++kt) {
            unsigned ea0 = (unsigned)__shfl((int)pk[2 * kt][0], src0);
            unsigned ea1 = (unsigned)__shfl((int)pk[2 * kt][1], src0);
            unsigned ea2 = (unsigned)__shfl((int)pk[2 * kt][0], src1);
            unsigned ea3 = (unsigned)__shfl((int)pk[2 * kt][1], src1);
            unsigned eb0 = (unsigned)__shfl((int)pk[2 * kt + 1][0], src0);
            unsigned eb1 = (unsigned)__shfl((int)pk[2 * kt + 1][1], src0);
            unsigned eb2 = (unsigned)__shfl((int)pk[2 * kt + 1][0], src1);
            unsigned eb3 = (unsigned)__shfl((int)pk[2 * kt + 1][1], src1);
            union { unsigned u[4]; bf16x8 v; } pu;
            pu.u[0] = up ? eb0 : ea0;
            pu.u[1] = up ? eb1 : ea1;
            pu.u[2] = up ? eb2 : ea2;
            pu.u[3] = up ? eb3 : ea3;
            #pragma unroll
            for (int dt = 0; dt < 2; ++dt) {
                bf16x8 vf = *(const bf16x8*)&sm.b.vt[h][dt * 16 + lr][kt * 32 + lq * 8];
                o[dt] = __builtin_amdgcn_mfma_f32_16x16x32_bf16(vf, pu.v, o[dt], 0, 0, 0);
            }
        }

        if (m < 49) {
            #pragma unroll
            for (int dt = 0; dt < 2; ++dt) {
                float4 v = make_float4(o[dt][0], o[dt][1], o[dt][2], o[dt][3]);
                *(float4*)&ob[m * 128 + h * 32 + dt * 16 + lq * 4] = v;
            }
        }
    }
}

extern "C" void kernel_launch(void* const* d_in, const int* in_sizes, int n_in,
                              void* d_out, int out_size, void* d_ws, size_t ws_size,
                              hipStream_t stream) {
    const float* x    = (const float*)d_in[0];
    const float* mask = (const float*)d_in[1];
    const float* qkvw = (const float*)d_in[2];
    const float* qkvb = (const float*)d_in[3];
    const float* relt = (const float*)d_in[4];
    float* out = (float*)d_out;

    if (d_ws != nullptr && ws_size >= (size_t)WS_NEED) {
        unsigned short* wbf = (unsigned short*)d_ws;
        float* bbf  = (float*)((char*)d_ws + WS_BIAS_OFF);
        float* comb = (float*)((char*)d_ws + WS_COMB_OFF);
        prep_kernel<<<3330, 256, 0, stream>>>(qkvw, qkvb, mask, relt, wbf, bbf, comb);
        wattn_ws<<<GRID_WS, 512, 0, stream>>>(x, wbf, bbf, comb, out);
    } else {
        wattn_fb<<<4096, 512, 0, stream>>>(x, mask, qkvw, qkvb, relt, out);
    }
}

// Round 11
// 269.917 us; speedup vs baseline: 1.8022x; 1.2306x over previous
//
#include <hip/hip_runtime.h>
#include <hip/hip_bf16.h>

// WindowAttention: B_=4096 windows, N=49, DIM=128, NH=4, HD=32, nW=64.
// One block per window, 512 threads = 8 waves; wave w -> (head = w&3, m-half = w>>2).
// bf16 MFMA 16x16x32. S computed transposed (S^T = K*Q^T): softmax rows in-lane,
// P feeds PV as B-fragment via shuffles (no P LDS round-trip).
// R10 = R6 (verified best: 149us wattn, clean counters) + hardware bf16 packing:
//  - all f32->bf16 pairs via __float22bfloat162_rn (v_cvt_pk_bf16_f32, 1 inst/2
//    values) read through a UNION (R4's __builtin_bit_cast on __hip_bfloat162
//    does not compile). Cuts ~700 VALU ops/wave/window (f2b was ~4 ops/value;
//    VALUBusy 26% was the largest busy pipe).
//  - zero structural change, zero added live registers (R5/R8/R9: any >=16
//    extra live regs across MFMA phases -> unified-file spill; never again).
// Tripwires: WRITE_SIZE >> 100 MB = spill; expect VALUBusy ~16-19%.

typedef short bf16x8 __attribute__((ext_vector_type(8)));
typedef float f32x4 __attribute__((ext_vector_type(4)));

#define DEVI __device__ __forceinline__

DEVI unsigned pack2(float lo, float hi) {   // 2x f32 -> packed bf16x2 (RNE, HW cvt_pk)
    union { __hip_bfloat162 h; unsigned u; } cv;
    cv.h = __float22bfloat162_rn(make_float2(lo, hi));
    return cv.u;
}

DEVI unsigned short f2b(float f) {          // single f32 -> bf16 bits (RNE)
    union { __hip_bfloat16 h; unsigned short u; } cv;
    cv.h = __float2bfloat16(f);
    return cv.u;
}

#define WS_BIAS_OFF 98304
#define WS_COMB_OFF 131072
#define COMB_ELEMS  802816u   // 256 * 49 * 64 (padded n-dim to 64)
#define WS_NEED     (131072u + COMB_ELEMS * 4u)

// prep: one element per thread.
//  g in [0, 49152)           : permuted bf16 weights, row c' = s*128+h*32+d
//  g in [49152, 49536)       : permuted (pre-scaled) bias
//  g in [49536, 49536+802816): comb[(w*4+h)][m][n64] = mask[w][m][n] + rel[m][n]
//                              (n in [49,64) baked to -1e30)
__global__ __launch_bounds__(256) void prep_kernel(
    const float* __restrict__ qkvw, const float* __restrict__ qkvb,
    const float* __restrict__ maskg, const float* __restrict__ relt,
    unsigned short* __restrict__ wb, float* __restrict__ bb,
    float* __restrict__ comb)
{
    const int g = blockIdx.x * 256 + threadIdx.x;
    if (g < 49152) {
        const int row = g >> 7, col = g & 127;
        const int s = row >> 7, r7 = row & 127, hh = r7 >> 5, d = r7 & 31;
        const int c = hh * 96 + d * 3 + s;          // torch row
        const float mul = (s == 0) ? 0.17677669529663687f : 1.0f;
        wb[row * 128 + col] = f2b(qkvw[c * 128 + col] * mul);
    } else if (g < 49536) {
        const int row = g - 49152;
        const int s = row >> 7, r7 = row & 127, hh = r7 >> 5, d = r7 & 31;
        const int c = hh * 96 + d * 3 + s;
        const float mul = (s == 0) ? 0.17677669529663687f : 1.0f;
        bb[row] = qkvb[c] * mul;
    } else {
        const unsigned g2 = (unsigned)(g - 49536);
        if (g2 < COMB_ELEMS) {
            const int wh = g2 / 3136;
            const int rr = g2 - wh * 3136;
            const int m = rr >> 6, n = rr & 63;
            const int w = wh >> 2, hh = wh & 3;
            float v = -1e30f;
            if (n < 49) {
                const int md = m / 7, mm = m - md * 7;
                const int nd = n / 7, nm = n - nd * 7;
                const int ridx = (md - nd + 6) * 13 + (mm - nm + 6);
                v = maskg[w * 2401 + m * 49 + n] + relt[ridx * 4 + hh];
            }
            comb[g2] = v;
        }
    }
}

// LDS: 32768 + 18432 = 51200 B -> 3 blocks/CU (24 waves/CU).
struct __align__(16) Smem {
    unsigned short qk[2][4][64][32];   // [q/k][head][m][d]; Q pre-scaled
    union {
        unsigned short xs[64][136];    // staged x, 272 B rows
        unsigned short vt[4][32][72];  // V^T [head][d][n], 144 B rows
    } b;
};

template <bool USE_WS>
__global__ __launch_bounds__(512, 6) void wattn_kernel(
    const float* __restrict__ xg, const unsigned short* __restrict__ wb,
    const float* __restrict__ bb, const float* __restrict__ comb,
    const float* __restrict__ maskg, const float* __restrict__ qkvw,
    const float* __restrict__ qkvb, const float* __restrict__ relt,
    float* __restrict__ outg)
{
    __shared__ Smem sm;
    const int tid  = threadIdx.x;
    const int lane = tid & 63;
    const int wv   = tid >> 6;       // 0..7
    const int h    = wv & 3;         // head
    const int half = wv >> 2;        // m-half
    const int lr   = lane & 15;
    const int lq   = lane >> 4;
    const int bI   = blockIdx.x;

    // ---------------- phase 0: stage x (bf16) into LDS ----------------
    const float* xb = xg + (size_t)bI * 6272;
    #pragma unroll
    for (int it = 0; it < 4; ++it) {
        int i = it * 512 + tid;
        if (i < 1568) {
            float4 v = ((const float4*)xb)[i];
            int row = i >> 5, col = (i & 31) << 2;
            *(uint2*)&sm.b.xs[row][col] = make_uint2(pack2(v.x, v.y), pack2(v.z, v.w));
        }
    }
    if (tid < 480) {                 // zero rows 49..63
        int idx = tid << 2;
        *(ushort4*)&sm.b.xs[49 + (idx >> 7)][idx & 127] = make_ushort4(0, 0, 0, 0);
    }
    __syncthreads();

    // ---------------- phase 1: QKV projection ----------------
    bf16x8 af[4][2];
    #pragma unroll
    for (int ks = 0; ks < 4; ++ks)
        #pragma unroll
        for (int mtl = 0; mtl < 2; ++mtl)
            af[ks][mtl] = *(const bf16x8*)&sm.b.xs[(half * 2 + mtl) * 16 + lr][ks * 32 + lq * 8];
    __syncthreads();                 // xs dead -> vt region may be written

    if constexpr (USE_WS) {
        // permuted weights: tile j -> (s = j>>1, dhalf = j&1), channel lane-linear
        #pragma unroll
        for (int j = 0; j < 6; ++j) {
            const int s     = j >> 1;
            const int dhalf = j & 1;
            const int cp    = s * 128 + h * 32 + dhalf * 16 + lr;
            const int dd    = dhalf * 16 + lr;
            const float bc  = bb[cp];
            f32x4 acc[2];
            acc[0] = f32x4{0.f, 0.f, 0.f, 0.f};
            acc[1] = f32x4{0.f, 0.f, 0.f, 0.f};
            #pragma unroll
            for (int ks = 0; ks < 4; ++ks) {
                bf16x8 bf = *(const bf16x8*)&wb[cp * 128 + ks * 32 + lq * 8];
                #pragma unroll
                for (int mtl = 0; mtl < 2; ++mtl)
                    acc[mtl] = __builtin_amdgcn_mfma_f32_16x16x32_bf16(af[ks][mtl], bf, acc[mtl], 0, 0, 0);
            }
            #pragma unroll
            for (int mtl = 0; mtl < 2; ++mtl) {
                const int m0 = (half * 2 + mtl) * 16 + lq * 4;
                const unsigned p01 = pack2(acc[mtl][0] + bc, acc[mtl][1] + bc);
                const unsigned p23 = pack2(acc[mtl][2] + bc, acc[mtl][3] + bc);
                if (s == 2) {
                    *(uint2*)&sm.b.vt[h][dd][m0] = make_uint2(p01, p23);
                } else {
                    sm.qk[s][h][m0 + 0][dd] = (unsigned short)p01;
                    sm.qk[s][h][m0 + 1][dd] = (unsigned short)(p01 >> 16);
                    sm.qk[s][h][m0 + 2][dd] = (unsigned short)p23;
                    sm.qk[s][h][m0 + 3][dd] = (unsigned short)(p23 >> 16);
                }
            }
        }
    } else {
        // fallback: unpermuted weights, scalar scatter (R2 path)
        unsigned short* sbase = (unsigned short*)&sm;
        #pragma unroll
        for (int j = 0; j < 6; ++j) {
            const int c = (h * 6 + j) * 16 + lr;
            const float bc = qkvb[c];
            const int rem = j * 16 + lr;
            const int dd = rem / 3, s = rem % 3;
            const float mulv = (s == 0) ? 0.17677669529663687f : 1.0f;
            f32x4 acc[2];
            acc[0] = f32x4{0.f, 0.f, 0.f, 0.f};
            acc[1] = f32x4{0.f, 0.f, 0.f, 0.f};
            #pragma unroll
            for (int ks = 0; ks < 4; ++ks) {
                const float4* wp = (const float4*)(qkvw + c * 128 + ks * 32 + lq * 8);
                float4 w0 = wp[0], w1 = wp[1];
                union { unsigned u[4]; bf16x8 v; } tw;
                tw.u[0] = pack2(w0.x, w0.y);
                tw.u[1] = pack2(w0.z, w0.w);
                tw.u[2] = pack2(w1.x, w1.y);
                tw.u[3] = pack2(w1.z, w1.w);
                #pragma unroll
                for (int mtl = 0; mtl < 2; ++mtl)
                    acc[mtl] = __builtin_amdgcn_mfma_f32_16x16x32_bf16(af[ks][mtl], tw.v, acc[mtl], 0, 0, 0);
            }
            #pragma unroll
            for (int mtl = 0; mtl < 2; ++mtl)
                #pragma unroll
                for (int r = 0; r < 4; ++r) {
                    int m = (half * 2 + mtl) * 16 + lq * 4 + r;
                    int soff = (s == 2) ? (16384 + (h * 32 + dd) * 72 + m)
                                        : (s * 8192 + h * 2048 + m * 32 + dd);
                    sbase[soff] = f2b((acc[mtl][r] + bc) * mulv);
                }
        }
    }
    __syncthreads();

    // ---------------- phase 2: attention ----------------
    bf16x8 kf[4];
    #pragma unroll
    for (int t = 0; t < 4; ++t)
        kf[t] = *(const bf16x8*)&sm.qk[1][h][t * 16 + lr][lq * 8];

    const float* cwh = comb + (size_t)((bI & 63) * 4 + h) * 3136;
    const float* mw  = maskg + (size_t)(bI & 63) * 2401;
    float* ob = outg + (size_t)bI * 6272;
    const int src0 = ((lq & 1) * 2) * 16 + lr;
    const int src1 = src0 + 16;
    const bool up  = (lq >= 2);

    #pragma unroll
    for (int bl = 0; bl < 2; ++bl) {
        const int mt = half * 2 + bl;
        const int m  = mt * 16 + lr;
        const int mi = m < 48 ? m : 48;

        f32x4 st[4];
        bf16x8 qf = *(const bf16x8*)&sm.qk[0][h][m][lq * 8];
        if constexpr (USE_WS) {
            // C-operand: comb[m][n] row, contiguous float4 over n (pads = -1e30)
            const float* cr = cwh + mi * 64;
            f32x4 cc[4];
            #pragma unroll
            for (int a = 0; a < 4; ++a)
                cc[a] = *(const f32x4*)&cr[a * 16 + lq * 4];
            #pragma unroll
            for (int a = 0; a < 4; ++a)
                st[a] = __builtin_amdgcn_mfma_f32_16x16x32_bf16(kf[a], qf, cc[a], 0, 0, 0);
        } else {
            #pragma unroll
            for (int a = 0; a < 4; ++a) {
                f32x4 z = f32x4{0.f, 0.f, 0.f, 0.f};
                st[a] = __builtin_amdgcn_mfma_f32_16x16x32_bf16(kf[a], qf, z, 0, 0, 0);
            }
            const int md = mi / 7, mm = mi - md * 7;
            #pragma unroll
            for (int a = 0; a < 4; ++a)
                #pragma unroll
                for (int r = 0; r < 4; ++r) {
                    int n = a * 16 + lq * 4 + r;
                    int ni = n < 48 ? n : 48;
                    int nd = ni / 7, nm = ni - nd * 7;
                    int ridx = (md - nd + 6) * 13 + (mm - nm + 6);
                    float v = st[a][r] + relt[ridx * 4 + h] + mw[mi * 49 + ni];
                    st[a][r] = (n < 49) ? v : -1e30f;
                }
        }

        // softmax over row m (16 in-lane + lanes {lr, lr+16, lr+32, lr+48})
        float mx = -3.4e38f;
        #pragma unroll
        for (int a = 0; a < 4; ++a)
            #pragma unroll
            for (int r = 0; r < 4; ++r) mx = fmaxf(mx, st[a][r]);
        mx = fmaxf(mx, __shfl_xor(mx, 16));
        mx = fmaxf(mx, __shfl_xor(mx, 32));
        float sum = 0.f;
        #pragma unroll
        for (int a = 0; a < 4; ++a)
            #pragma unroll
            for (int r = 0; r < 4; ++r) {
                float e = __expf(st[a][r] - mx);
                st[a][r] = e;
                sum += e;
            }
        sum += __shfl_xor(sum, 16);
        sum += __shfl_xor(sum, 32);
        const float inv = 1.f / sum;

        unsigned pk[4][2];
        #pragma unroll
        for (int a = 0; a < 4; ++a) {
            pk[a][0] = pack2(st[a][0] * inv, st[a][1] * inv);
            pk[a][1] = pack2(st[a][2] * inv, st[a][3] * inv);
        }

        // PV: out^T[d][m] = sum_n Vt[d][n] * P[m][n]; P B-frag via shuffles
        f32x4 o[2];
        o[0] = f32x4{0.f, 0.f, 0.f, 0.f};
        o[1] = f32x4{0.f, 0.f, 0.f, 0.f};
        #pragma unroll
        for (int kt = 0; kt < 2; ++kt) {
            unsigned ea0 = (unsigned)__shfl((int)pk[2 * kt][0], src0);
            unsigned ea1 = (unsigned)__shfl((int)pk[2 * kt][1], src0);
            unsigned ea2 = (unsigned)__shfl((int)pk[2 * kt][0], src1);
            unsigned ea3 = (unsigned)__shfl((int)pk[2 * kt][1], src1);
            unsigned eb0 = (unsigned)__shfl((int)pk[2 * kt + 1][0], src0);
            unsigned eb1 = (unsigned)__shfl((int)pk[2 * kt + 1][1], src0);
            unsigned eb2 = (unsigned)__shfl((int)pk[2 * kt + 1][0], src1);
            unsigned eb3 = (unsigned)__shfl((int)pk[2 * kt + 1][1], src1);
            union { unsigned u[4]; bf16x8 v; } pu;
            pu.u[0] = up ? eb0 : ea0;
            pu.u[1] = up ? eb1 : ea1;
            pu.u[2] = up ? eb2 : ea2;
            pu.u[3] = up ? eb3 : ea3;
            #pragma unroll
            for (int dt = 0; dt < 2; ++dt) {
                bf16x8 vf = *(const bf16x8*)&sm.b.vt[h][dt * 16 + lr][kt * 32 + lq * 8];
                o[dt] = __builtin_amdgcn_mfma_f32_16x16x32_bf16(vf, pu.v, o[dt], 0, 0, 0);
            }
        }

        if (m < 49) {
            #pragma unroll
            for (int dt = 0; dt < 2; ++dt) {
                float4 v = make_float4(o[dt][0], o[dt][1], o[dt][2], o[dt][3]);
                *(float4*)&ob[m * 128 + h * 32 + dt * 16 + lq * 4] = v;
            }
        }
    }
}

extern "C" void kernel_launch(void* const* d_in, const int* in_sizes, int n_in,
                              void* d_out, int out_size, void* d_ws, size_t ws_size,
                              hipStream_t stream) {
    const float* x    = (const float*)d_in[0];
    const float* mask = (const float*)d_in[1];
    const float* qkvw = (const float*)d_in[2];
    const float* qkvb = (const float*)d_in[3];
    const float* relt = (const float*)d_in[4];
    float* out = (float*)d_out;

    if (d_ws != nullptr && ws_size >= (size_t)WS_NEED) {
        unsigned short* wbf = (unsigned short*)d_ws;
        float* bbf  = (float*)((char*)d_ws + WS_BIAS_OFF);
        float* comb = (float*)((char*)d_ws + WS_COMB_OFF);
        // elements: 49152 weights + 384 bias + 802816 comb = 852352 -> 3330 blocks
        prep_kernel<<<3330, 256, 0, stream>>>(qkvw, qkvb, mask, relt, wbf, bbf, comb);
        wattn_kernel<true><<<4096, 512, 0, stream>>>(x, wbf, bbf, comb, mask, qkvw, qkvb, relt, out);
    } else {
        wattn_kernel<false><<<4096, 512, 0, stream>>>(x, nullptr, nullptr, nullptr, mask, qkvw, qkvb, relt, out);
    }
}